// Round 2
// baseline (558.967 us; speedup 1.0000x reference)
//
#include <hip/hip_runtime.h>
#include <hip/hip_bf16.h>

// B=32, N=36, D=2048, C=4, H=512.  K = 2H = 1024 stacked (coord|feat).
// Out[b,i,d] = max_j sum_k Wcat[k,d] * (crfr[b,j,k] * clfl[b,i,k]) + mm[b,i,d]
// v2: k_prod fused into k_pairwise (products computed in-block into LDS),
//     Lw/Rw kept f32, BK=64 per barrier phase, issue-early/consume-late staging.
// v2.1: __builtin_bit_cast -> __builtin_memcpy (gfx950 clang rejects bit_cast
//       of __hip_bfloat162).

typedef __attribute__((ext_vector_type(8))) short short8;
typedef __attribute__((ext_vector_type(4))) short short4v;
typedef __attribute__((ext_vector_type(4))) float f32x4;
typedef __attribute__((ext_vector_type(8))) float f32x8;
typedef __attribute__((ext_vector_type(4))) unsigned int u32x4;

__device__ __forceinline__ unsigned short f2bf(float f) {
  unsigned int u = __float_as_uint(f);
  u += 0x7FFFu + ((u >> 16) & 1u);
  return (unsigned short)(u >> 16);
}

// 8 products a[e]*b[e] -> bf16 RNE, packed as 4 dwords (compiler emits cvt_pk)
__device__ __forceinline__ u32x4 pack8(f32x8 a, f32x8 b) {
  u32x4 o;
#pragma unroll
  for (int e2 = 0; e2 < 4; ++e2) {
    __hip_bfloat162 h = __float22bfloat162_rn(
        make_float2(a[2 * e2] * b[2 * e2], a[2 * e2 + 1] * b[2 * e2 + 1]));
    unsigned int u;
    __builtin_memcpy(&u, &h, sizeof(u));
    o[e2] = u;
  }
  return o;
}

// ---------------------------------------------------------------------------
// K_prep: bid<2304: coords proj (cl->Lw[:,0:512], cr->Rw[:,0:512]) + mm->bf16.
//         bid>=2304: weights -> MFMA fragment order (WS for K4, WS2 for K3).
__global__ __launch_bounds__(256) void k_prep(
    const float* __restrict__ coords, const float* __restrict__ Wcl,
    const float* __restrict__ Wcr, const float* __restrict__ mm,
    const float* __restrict__ Wcout, const float* __restrict__ Wfout,
    const float* __restrict__ Wfl, const float* __restrict__ Wfr,
    float* __restrict__ Lw, float* __restrict__ Rw,
    unsigned short* __restrict__ mmb, unsigned short* __restrict__ WS,
    unsigned short* __restrict__ WS2) {
  const int bid = blockIdx.x;
  if (bid < 2304) {
    int idx = bid * 256 + threadIdx.x;  // 0 .. 1152*512-1
    int row = idx >> 9, h = idx & 511;
    const float* c = coords + row * 4;
    float a0 = c[0], a1 = c[1], a2 = c[2], a3 = c[3];
    float vl = a0 * Wcl[h] + a1 * Wcl[512 + h] + a2 * Wcl[1024 + h] + a3 * Wcl[1536 + h];
    float vr = a0 * Wcr[h] + a1 * Wcr[512 + h] + a2 * Wcr[1024 + h] + a3 * Wcr[1536 + h];
    Lw[(size_t)row * 1024 + h] = vl;
    Rw[(size_t)row * 1024 + h] = vr;
    float4 m4 = *(const float4*)(mm + (size_t)row * 2048 + h * 4);
    short4v o;
    o[0] = (short)f2bf(m4.x); o[1] = (short)f2bf(m4.y);
    o[2] = (short)f2bf(m4.z); o[3] = (short)f2bf(m4.w);
    *(short4v*)(mmb + (size_t)row * 2048 + h * 4) = o;
  } else {
    int gi = (bid - 2304) * 256 + threadIdx.x;  // 0..524287
    if (gi < 262144) {
      // WS granule gi = ((g2*32+kc)*4+q)*16+n ; elem e: d=g2*16+n, k=kc*32+q*8+e
      int n = gi & 15, qv = (gi >> 4) & 3, kc = (gi >> 6) & 31, g2 = gi >> 11;
      int d = g2 * 16 + n;
      int kbase = kc * 32 + qv * 8;
      const float* src = (kbase < 512) ? (Wcout + (size_t)kbase * 2048 + d)
                                       : (Wfout + (size_t)(kbase - 512) * 2048 + d);
      short8 o;
#pragma unroll
      for (int e = 0; e < 8; ++e) o[e] = (short)f2bf(src[(size_t)e * 2048]);
      *(short8*)(WS + (size_t)gi * 8) = o;
    } else {
      // WS2 granule gj = ((cg*64+kc)*4+q)*16+n ; elem e: col=cg*16+n, dd=kc*32+q*8+e
      int gj = gi - 262144;
      int n = gj & 15, qv = (gj >> 4) & 3, kc = (gj >> 6) & 63, cg = gj >> 12;
      int col = cg * 16 + n;
      int dbase = kc * 32 + qv * 8;
      const float* src = (col < 512) ? (Wfl + (size_t)dbase * 512 + col)
                                     : (Wfr + (size_t)dbase * 512 + (col - 512));
      short8 o;
#pragma unroll
      for (int e = 0; e < 8; ++e) o[e] = (short)f2bf(src[(size_t)e * 512]);
      *(short8*)(WS2 + (size_t)gj * 8) = o;
    }
  }
}

// ---------------------------------------------------------------------------
// K3: feature projection O[row,col] = sum_dd mmb[row,dd]*Wlr[dd,col]
//  col<512 -> fl -> Lw[row][512+col] ; else fr -> Rw[row][col]   (f32 out)
__global__ __launch_bounds__(256) void k_proj_feat(
    const unsigned short* __restrict__ mmb, const unsigned short* __restrict__ WS2,
    float* __restrict__ Lw, float* __restrict__ Rw) {
  const int tid = threadIdx.x;
  const int lane = tid & 63, w = tid >> 6;
  const int n = lane & 15, q = lane >> 4;
  const int m0 = blockIdx.y * 16;
  const int cg = blockIdx.x * 4 + w;  // 0..63
  const int c0 = cg * 16;

  f32x4 acc = {0.f, 0.f, 0.f, 0.f};
#pragma unroll 4
  for (int kc = 0; kc < 64; ++kc) {
    short8 a = *(const short8*)(mmb + (size_t)(m0 + n) * 2048 + kc * 32 + q * 8);
    short8 b = *(const short8*)(WS2 + (size_t)(cg * 64 + kc) * 512 + lane * 8);
    acc = __builtin_amdgcn_mfma_f32_16x16x32_bf16(a, b, acc, 0, 0, 0);
  }
#pragma unroll
  for (int e = 0; e < 4; ++e) {
    int row = m0 + q * 4 + e;
    int col = c0 + n;
    if (col < 512) Lw[(size_t)row * 1024 + 512 + col] = acc[e];
    else           Rw[(size_t)row * 1024 + col] = acc[e];
  }
}

// ---------------------------------------------------------------------------
// K4 (fused): streaming GEMM + in-block pair-product staging + max-over-j +
// residual. Block: 512 thr (8 waves), one quad-group x 256-d tile.
// grid 2304 = qg*8+dt (bx%8=dt -> per-XCD W-slice stays L2-resident).
// Per phase (64 k = 2 kc-chunks): issue product loads (f32, L2-resident Lw/Rw)
// + next A frags EARLY; run 36 MFMA/wave; then mul+cvt_pk+ds_write the 18
// B-granules for the NEXT phase into the other LDS buffer; __syncthreads.
// Product fragment layout identical to the old k_prod: granule t, lane (q,n),
// elem e: k=kc*32+q*8+e; t<8: g=qg*4+(t>>1), j=(t&1)*16+n; t=8 (shared
// remainder): g=qg*4+(n>>2), j=32+(n&3). Granule 8 is load-balanced: wave w's
// lanes 0..7 produce its slot l = w*8+lane.
__global__ __launch_bounds__(512, 2) void k_pairwise(
    const float* __restrict__ Lw, const float* __restrict__ Rw,
    const unsigned short* __restrict__ WS, const float* __restrict__ mm,
    float* __restrict__ out) {
  __shared__ __align__(16) unsigned short lB[2][2 * 9 * 512];  // 2 x 18 KB

  const int tid = threadIdx.x;
  const int lane = tid & 63, w = tid >> 6;  // w 0..7
  const int n = lane & 15, q = lane >> 4;
  const int bx = blockIdx.x;
  const int dt = bx & 7, qg = bx >> 3;  // dt 0..7, qg 0..287
  const int g0 = qg * 4;
  const int b36 = (qg / 9) * 36;

  // primary product slot: granule t=w, lane l=lane
  const int g_p = g0 + (w >> 1);
  const int j_p = (w & 1) * 16 + n;
  // secondary slot (granule 8), handled by lanes 0..7 of every wave:
  const int ls = w * 8 + (lane & 7);
  const int qs = ls >> 4, ns = ls & 15;
  const int g_s = g0 + (ns >> 2);
  const int j_s = 32 + (ns & 3);

  const float* Lp = Lw + (size_t)g_p * 1024 + q * 8;
  const float* Rp = Rw + (size_t)(b36 + j_p) * 1024 + q * 8;
  const float* Ls = Lw + (size_t)g_s * 1024 + qs * 8;
  const float* Rs = Rw + (size_t)(b36 + j_s) * 1024 + qs * 8;

  f32x4 acc[9][2];
#pragma unroll
  for (int t = 0; t < 9; ++t)
#pragma unroll
    for (int r = 0; r < 2; ++r) acc[t][r] = (f32x4){0.f, 0.f, 0.f, 0.f};

  // A granule (r, kc): WS + ((dt*16 + w*2 + r)*32 + kc)*512 + lane*8
  const unsigned short* Abase = WS + ((size_t)(dt * 16 + w * 2) * 32) * 512 + lane * 8;

  short8 aC[2][2];  // [kci][r] current-phase A fragments

  // ---- prologue: A(kc=0,1) + products for phase 0 into lB[0]
#pragma unroll
  for (int kci = 0; kci < 2; ++kci) {
#pragma unroll
    for (int r = 0; r < 2; ++r)
      aC[kci][r] = *(const short8*)(Abase + (size_t)(r * 32 + kci) * 512);
    f32x8 c0 = *(const f32x8*)(Lp + kci * 32);
    f32x8 r0 = *(const f32x8*)(Rp + kci * 32);
    *(u32x4*)(&lB[0][kci * 4608 + w * 512 + lane * 8]) = pack8(c0, r0);
    if ((lane & 63) < 8) {
      f32x8 c1 = *(const f32x8*)(Ls + kci * 32);
      f32x8 r1 = *(const f32x8*)(Rs + kci * 32);
      *(u32x4*)(&lB[0][kci * 4608 + 8 * 512 + ls * 8]) = pack8(c1, r1);
    }
  }
  __syncthreads();

  for (int p = 0; p < 16; ++p) {
    const int buf = p & 1;
    const bool pre = (p < 15);
    f32x8 pcl[2], pcr[2], scl[2], scr[2];
    short8 aN[2][2];
    if (pre) {
      const int kb = (p + 1) * 2;
      // issue-early: all loads for phase p+1 (consumed after the MFMA block)
#pragma unroll
      for (int kci = 0; kci < 2; ++kci) {
#pragma unroll
        for (int r = 0; r < 2; ++r)
          aN[kci][r] = *(const short8*)(Abase + (size_t)(r * 32 + kb + kci) * 512);
        pcl[kci] = *(const f32x8*)(Lp + (kb + kci) * 32);
        pcr[kci] = *(const f32x8*)(Rp + (kb + kci) * 32);
        if ((lane & 63) < 8) {
          scl[kci] = *(const f32x8*)(Ls + (kb + kci) * 32);
          scr[kci] = *(const f32x8*)(Rs + (kb + kci) * 32);
        }
      }
    }
    // ---- 36 MFMA on phase p (kc = 2p, 2p+1)
#pragma unroll
    for (int t = 0; t < 9; ++t) {
      short8 b0 = *(const short8*)(&lB[buf][t * 512 + lane * 8]);
      short8 b1 = *(const short8*)(&lB[buf][4608 + t * 512 + lane * 8]);
      acc[t][0] = __builtin_amdgcn_mfma_f32_16x16x32_bf16(aC[0][0], b0, acc[t][0], 0, 0, 0);
      acc[t][1] = __builtin_amdgcn_mfma_f32_16x16x32_bf16(aC[0][1], b0, acc[t][1], 0, 0, 0);
      acc[t][0] = __builtin_amdgcn_mfma_f32_16x16x32_bf16(aC[1][0], b1, acc[t][0], 0, 0, 0);
      acc[t][1] = __builtin_amdgcn_mfma_f32_16x16x32_bf16(aC[1][1], b1, acc[t][1], 0, 0, 0);
    }
    if (pre) {
      // consume-late: products for phase p+1 -> lB[buf^1]
#pragma unroll
      for (int kci = 0; kci < 2; ++kci) {
        *(u32x4*)(&lB[buf ^ 1][kci * 4608 + w * 512 + lane * 8]) = pack8(pcl[kci], pcr[kci]);
        if ((lane & 63) < 8)
          *(u32x4*)(&lB[buf ^ 1][kci * 4608 + 8 * 512 + ls * 8]) = pack8(scl[kci], scr[kci]);
      }
    }
    __syncthreads();  // lB[buf^1] complete; all reads of lB[buf] done
    if (pre) {
#pragma unroll
      for (int kci = 0; kci < 2; ++kci)
#pragma unroll
        for (int r = 0; r < 2; ++r) aC[kci][r] = aN[kci][r];
    }
  }

  // epilogue: per (ii,r,e): max over full tiles 2ii,2ii+1 (j=n, 16+n) and the
  // shared tile's lanes with n>>2==ii (j=32+(n&3)); xor-reduce over 16 n-lanes.
#pragma unroll
  for (int r = 0; r < 2; ++r) {
#pragma unroll
    for (int e = 0; e < 4; ++e) {
      float vs = acc[8][r][e];
#pragma unroll
      for (int ii = 0; ii < 4; ++ii) {
        float v = fmaxf(acc[ii * 2][r][e], acc[ii * 2 + 1][r][e]);
        v = fmaxf(v, ((n >> 2) == ii) ? vs : -1e30f);
#pragma unroll
        for (int s = 1; s < 16; s <<= 1) v = fmaxf(v, __shfl_xor(v, s, 64));
        if (n == 0) {
          int d = dt * 256 + w * 32 + r * 16 + q * 4 + e;
          size_t o = (size_t)(g0 + ii) * 2048 + d;
          out[o] = v + mm[o];
        }
      }
    }
  }
}

// ---------------------------------------------------------------------------
extern "C" void kernel_launch(void* const* d_in, const int* in_sizes, int n_in,
                              void* d_out, int out_size, void* d_ws, size_t ws_size,
                              hipStream_t stream) {
  const float* mm     = (const float*)d_in[0];
  const float* coords = (const float*)d_in[1];
  const float* Wcl    = (const float*)d_in[2];
  const float* Wcr    = (const float*)d_in[3];
  const float* Wcout  = (const float*)d_in[4];
  const float* Wfl    = (const float*)d_in[5];
  const float* Wfr    = (const float*)d_in[6];
  const float* Wfout  = (const float*)d_in[7];
  float* out = (float*)d_out;

  // workspace, ~22 MB total (was ~103 MB: Pf eliminated)
  float* Lw = (float*)d_ws;                       // [1152][1024] f32  cl | fl
  float* Rw = Lw + (size_t)1152 * 1024;           // [1152][1024] f32  cr | fr
  unsigned short* WS  = (unsigned short*)(Rw + (size_t)1152 * 1024);  // 262144 gran x 8 (Wcat^T frag)
  unsigned short* WS2 = WS + (size_t)262144 * 8;  // 262144 gran x 8 ((Wfl|Wfr)^T frag)
  unsigned short* mmb = WS2 + (size_t)262144 * 8; // [1152][2048] mm bf16

  k_prep<<<2304 + 2048, 256, 0, stream>>>(coords, Wcl, Wcr, mm, Wcout, Wfout,
                                          Wfl, Wfr, Lw, Rw, mmb, WS, WS2);
  k_proj_feat<<<dim3(16, 72), 256, 0, stream>>>(mmb, WS2, Lw, Rw);
  k_pairwise<<<2304, 512, 0, stream>>>(Lw, Rw, WS, mm, out);
}

// Round 3
// 384.250 us; speedup vs baseline: 1.4547x; 1.4547x over previous
//
#include <hip/hip_runtime.h>

// B=32, N=36, D=2048, C=4, H=512.
// Out[b,i,d] = max_j [ sum_k Wfout[k,d]*(fl[i,k]*fr[j,k])
//                    + sum_ab Mc[ab,d]*(coords[i,a]*coords[j,b]) ] + mm[b,i,d]
// v3: coord branch collapsed via Mc[ab,d] = sum_h Wcl[a,h]Wcr[b,h]Wcout[h,d]
//     (rank-4 coords -> K_coord = 16, zero-padded to one K=32 chunk).
//     K: 1024 -> 544 = 17 kc-chunks. k_pairwise structure identical to the
//     proven v1 (56 VGPR, 2 blocks/CU, global_load_lds dbuf staging).

typedef __attribute__((ext_vector_type(8))) short short8;
typedef __attribute__((ext_vector_type(4))) short short4v;
typedef __attribute__((ext_vector_type(4))) float f32x4;

__device__ __forceinline__ float bf2f(unsigned short h) {
  return __uint_as_float(((unsigned int)h) << 16);
}
__device__ __forceinline__ unsigned short f2bf(float f) {
  unsigned int u = __float_as_uint(f);
  u += 0x7FFFu + ((u >> 16) & 1u);
  return (unsigned short)(u >> 16);
}
// async global->LDS, 16B per lane; lds dest is wave-uniform base + lane*16
__device__ __forceinline__ void gl2lds16(const void* g, void* l) {
  __builtin_amdgcn_global_load_lds(
      (const __attribute__((address_space(1))) unsigned int*)g,
      (__attribute__((address_space(3))) unsigned int*)l, 16, 0, 0);
}

// ---------------------------------------------------------------------------
// K_mc: Mc[ab][d] = sum_h Wcl[a,h] * Wcr[b,h] * Wcout[h,d]   (f32, 16x2048)
// grid 8 x 256 threads; thread = one d column, all 16 ab outputs.
__global__ __launch_bounds__(256) void k_mc(
    const float* __restrict__ Wcl, const float* __restrict__ Wcr,
    const float* __restrict__ Wcout, float* __restrict__ Mc) {
  const int d = blockIdx.x * 256 + threadIdx.x;
  float acc[16];
#pragma unroll
  for (int i = 0; i < 16; ++i) acc[i] = 0.f;
  for (int h = 0; h < 512; ++h) {
    float wo = Wcout[(size_t)h * 2048 + d];
    float cl[4], cr[4];
#pragma unroll
    for (int a = 0; a < 4; ++a) {
      cl[a] = Wcl[a * 512 + h];
      cr[a] = Wcr[a * 512 + h];
    }
#pragma unroll
    for (int a = 0; a < 4; ++a) {
      float t = cl[a] * wo;
#pragma unroll
      for (int b = 0; b < 4; ++b) acc[a * 4 + b] += t * cr[b];
    }
  }
#pragma unroll
  for (int ab = 0; ab < 16; ++ab) Mc[(size_t)ab * 2048 + d] = acc[ab];
}

// ---------------------------------------------------------------------------
// K_prep: bid<2304: mm -> bf16 (mmb).
//         bid>=2304: weights -> MFMA fragment order:
//           WS  (A for k_pairwise): kc<16 from Wfout[k,d] (k=kc*32+q*8+e),
//                                   kc==16 from Mc[kk,d] (kk=q*8+e<16, else 0)
//           WS2 (B for k_proj_feat): (Wfl|Wfr)^T fragments (unchanged).
__global__ __launch_bounds__(256) void k_prep(
    const float* __restrict__ mm, const float* __restrict__ Wfout,
    const float* __restrict__ Mc, const float* __restrict__ Wfl,
    const float* __restrict__ Wfr, unsigned short* __restrict__ mmb,
    unsigned short* __restrict__ WS, unsigned short* __restrict__ WS2) {
  const int bid = blockIdx.x;
  if (bid < 2304) {
    int idx = bid * 256 + threadIdx.x;  // 0 .. 1152*512-1
    int row = idx >> 9, h = idx & 511;
    float4 m4 = *(const float4*)(mm + (size_t)row * 2048 + h * 4);
    short4v o;
    o[0] = (short)f2bf(m4.x); o[1] = (short)f2bf(m4.y);
    o[2] = (short)f2bf(m4.z); o[3] = (short)f2bf(m4.w);
    *(short4v*)(mmb + (size_t)row * 2048 + h * 4) = o;
  } else {
    int gi = (bid - 2304) * 256 + threadIdx.x;  // 0..401407
    if (gi < 139264) {
      // WS granule gi = ((g2*17+kc)*4+q)*16+n ; elem e: d=g2*16+n, k=kc*32+q*8+e
      int n = gi & 15, qv = (gi >> 4) & 3, rest = gi >> 6;
      int kc = rest % 17, g2 = rest / 17;
      int d = g2 * 16 + n;
      short8 o;
      if (kc < 16) {
        int kbase = kc * 32 + qv * 8;
        const float* src = Wfout + (size_t)kbase * 2048 + d;
#pragma unroll
        for (int e = 0; e < 8; ++e) o[e] = (short)f2bf(src[(size_t)e * 2048]);
      } else if (qv < 2) {
        const float* src = Mc + (size_t)(qv * 8) * 2048 + d;
#pragma unroll
        for (int e = 0; e < 8; ++e) o[e] = (short)f2bf(src[(size_t)e * 2048]);
      } else {
#pragma unroll
        for (int e = 0; e < 8; ++e) o[e] = 0;
      }
      *(short8*)(WS + (size_t)gi * 8) = o;
    } else {
      // WS2 granule gj = ((cg*64+kc)*4+q)*16+n ; elem e: col=cg*16+n, dd=kc*32+q*8+e
      int gj = gi - 139264;
      int n = gj & 15, qv = (gj >> 4) & 3, kc = (gj >> 6) & 63, cg = gj >> 12;
      int col = cg * 16 + n;
      int dbase = kc * 32 + qv * 8;
      const float* src = (col < 512) ? (Wfl + (size_t)dbase * 512 + col)
                                     : (Wfr + (size_t)dbase * 512 + (col - 512));
      short8 o;
#pragma unroll
      for (int e = 0; e < 8; ++e) o[e] = (short)f2bf(src[(size_t)e * 512]);
      *(short8*)(WS2 + (size_t)gj * 8) = o;
    }
  }
}

// ---------------------------------------------------------------------------
// K3: feature projection O[row,col] = sum_dd mmb[row,dd]*Wlr[dd,col]
//  col<512 -> Fl[row][col] ; else -> Fr[row][col-512]   (bf16 out)
__global__ __launch_bounds__(256) void k_proj_feat(
    const unsigned short* __restrict__ mmb, const unsigned short* __restrict__ WS2,
    unsigned short* __restrict__ Fl, unsigned short* __restrict__ Fr) {
  const int tid = threadIdx.x;
  const int lane = tid & 63, w = tid >> 6;
  const int n = lane & 15, q = lane >> 4;
  const int m0 = blockIdx.y * 16;
  const int cg = blockIdx.x * 4 + w;  // 0..63
  const int c0 = cg * 16;

  f32x4 acc = {0.f, 0.f, 0.f, 0.f};
#pragma unroll 4
  for (int kc = 0; kc < 64; ++kc) {
    short8 a = *(const short8*)(mmb + (size_t)(m0 + n) * 2048 + kc * 32 + q * 8);
    short8 b = *(const short8*)(WS2 + (size_t)(cg * 64 + kc) * 512 + lane * 8);
    acc = __builtin_amdgcn_mfma_f32_16x16x32_bf16(a, b, acc, 0, 0, 0);
  }
#pragma unroll
  for (int e = 0; e < 4; ++e) {
    int row = m0 + q * 4 + e;
    int col = c0 + n;
    unsigned short v = f2bf(acc[e]);
    if (col < 512) Fl[(size_t)row * 512 + col] = v;
    else           Fr[(size_t)row * 512 + (col - 512)] = v;
  }
}

// ---------------------------------------------------------------------------
// K_prod: materialize pair "products" in MFMA B-fragment order, quad-packed.
// Granule id = (qg*17 + kc)*9 + t ; lane (q,n), elem e: k = kc*32 + q*8 + e.
//   t<8 : group g = qg*4 + (t>>1), col j = (t&1)*16 + n      (full tiles)
//   t=8 : group g = qg*4 + (n>>2), col j = 32 + (n&3)        (shared remainder)
// kc<16 : P = Fl[g,k] * Fr[b*36+j,k]                (feature products)
// kc==16: P = coords[g,a]*coords[b*36+j,bb], ab=q*8+e (<16), else 0 (coord cc)
__global__ __launch_bounds__(256) void k_prod(
    const unsigned short* __restrict__ Fl, const unsigned short* __restrict__ Fr,
    const float* __restrict__ coords, unsigned short* __restrict__ Pf) {
  int idx = blockIdx.x * 256 + threadIdx.x;  // 0 .. 2,820,095
  int lane = idx & 63;
  int gran = idx >> 6;          // 0 .. 44063
  int qg = gran / 153;          // 153 = 17 kc * 9 t granules per quad-group
  int rem = gran - qg * 153;
  int kc = rem / 9;
  int t = rem - kc * 9;
  int n = lane & 15, q = lane >> 4;
  int b = qg / 9;
  int g, j;
  if (t < 8) { g = qg * 4 + (t >> 1); j = (t & 1) * 16 + n; }
  else       { g = qg * 4 + (n >> 2); j = 32 + (n & 3); }
  int rowj = b * 36 + j;
  short8 p;
  if (kc < 16) {
    int k0 = kc * 32 + q * 8;
    short8 cl8 = *(const short8*)(Fl + (size_t)g * 512 + k0);
    short8 cr8 = *(const short8*)(Fr + (size_t)rowj * 512 + k0);
#pragma unroll
    for (int e = 0; e < 8; ++e)
      p[e] = (short)f2bf(bf2f((unsigned short)cl8[e]) * bf2f((unsigned short)cr8[e]));
  } else if (q < 2) {
    float4 ci = *(const float4*)(coords + (size_t)g * 4);
    float4 cj = *(const float4*)(coords + (size_t)rowj * 4);
#pragma unroll
    for (int e = 0; e < 8; ++e) {
      int a = q * 2 + (e >> 2);  // 0..3 (q<2)
      float ca = (a == 0) ? ci.x : (a == 1) ? ci.y : (a == 2) ? ci.z : ci.w;
      float cb = ((e & 3) == 0) ? cj.x : ((e & 3) == 1) ? cj.y
               : ((e & 3) == 2) ? cj.z : cj.w;
      p[e] = (short)f2bf(ca * cb);
    }
  } else {
#pragma unroll
    for (int e = 0; e < 8; ++e) p[e] = 0;
  }
  *(short8*)(Pf + (size_t)idx * 8) = p;
}

// ---------------------------------------------------------------------------
// K4: streaming GEMM + max-over-j + residual. Identical structure to the
// proven v1 kernel, with NK = 17 kc-chunks (K = 544). Block: 512 thr
// (8 waves), one quad-group x 256-d tile. grid 2304 = qg*8+dt. Per chunk
// (32 k): stage 9 B-granules (9KB) via global_load_lds into dbuf LDS, 2
// A-granules/wave from WS (reg dbuf), 18 MFMA/wave. acc 72 AGPR.
__global__ __launch_bounds__(512, 2) void k_pairwise(
    const unsigned short* __restrict__ Pf, const unsigned short* __restrict__ WS,
    const float* __restrict__ mm, float* __restrict__ out) {
  __shared__ __align__(16) unsigned short lB[2][9 * 512];  // 2 x 9 KB

  const int tid = threadIdx.x;
  const int lane = tid & 63, w = tid >> 6;  // w 0..7
  const int n = lane & 15, q = lane >> 4;
  const int bx = blockIdx.x;
  const int dt = bx & 7, qg = bx >> 3;  // dt 0..7, qg 0..287
  const int g0 = qg * 4;

  f32x4 acc[9][2];
#pragma unroll
  for (int t = 0; t < 9; ++t)
#pragma unroll
    for (int r = 0; r < 2; ++r) acc[t][r] = (f32x4){0.f, 0.f, 0.f, 0.f};

  // A granule (r, kc): WS + ((dt*16 + w*2 + r)*17 + kc)*512 + lane*8
  const unsigned short* Abase = WS + ((size_t)(dt * 16 + w * 2) * 17) * 512 + lane * 8;
  // B granule (kc, t): Pf + ((qg*17 + kc)*9 + t)*512 + lane*8
  const unsigned short* Bbase = Pf + (size_t)qg * 17 * 9 * 512;

  short8 aR[2], aN[2];
  // prologue: stage kc=0, load A(kc=0)
  gl2lds16(Bbase + (size_t)w * 512 + lane * 8, &lB[0][w * 512]);
  if (w == 0) gl2lds16(Bbase + (size_t)8 * 512 + lane * 8, &lB[0][8 * 512]);
  aR[0] = *(const short8*)(Abase);
  aR[1] = *(const short8*)(Abase + 17 * 512);
  __syncthreads();  // vmcnt(0) drain before barrier -> lB[0] ready

#pragma unroll 2
  for (int kc = 0; kc < 17; ++kc) {
    const int buf = kc & 1;
    if (kc < 16) {
      const unsigned short* bn = Bbase + (size_t)((kc + 1) * 9) * 512 + lane * 8;
      gl2lds16(bn + (size_t)w * 512, &lB[buf ^ 1][w * 512]);
      if (w == 0) gl2lds16(bn + (size_t)8 * 512, &lB[buf ^ 1][8 * 512]);
      aN[0] = *(const short8*)(Abase + (size_t)(kc + 1) * 512);
      aN[1] = *(const short8*)(Abase + (size_t)(17 + kc + 1) * 512);
    }
    short8 bb[9];
#pragma unroll
    for (int t = 0; t < 9; ++t)
      bb[t] = *(const short8*)(&lB[buf][t * 512 + lane * 8]);
#pragma unroll
    for (int t = 0; t < 9; ++t) {
      acc[t][0] = __builtin_amdgcn_mfma_f32_16x16x32_bf16(aR[0], bb[t], acc[t][0], 0, 0, 0);
      acc[t][1] = __builtin_amdgcn_mfma_f32_16x16x32_bf16(aR[1], bb[t], acc[t][1], 0, 0, 0);
    }
    __syncthreads();  // all waves done reading buf; staged buf^1 complete
    aR[0] = aN[0];
    aR[1] = aN[1];
  }

  // epilogue: per (ii,r,e): max over full tiles 2ii,2ii+1 (j=n, 16+n) and the
  // shared tile's lanes with n>>2==ii (j=32+(n&3)); xor-reduce over 16 n-lanes.
#pragma unroll
  for (int r = 0; r < 2; ++r) {
#pragma unroll
    for (int e = 0; e < 4; ++e) {
      float vs = acc[8][r][e];
#pragma unroll
      for (int ii = 0; ii < 4; ++ii) {
        float v = fmaxf(acc[ii * 2][r][e], acc[ii * 2 + 1][r][e]);
        v = fmaxf(v, ((n >> 2) == ii) ? vs : -1e30f);
#pragma unroll
        for (int s = 1; s < 16; s <<= 1) v = fmaxf(v, __shfl_xor(v, s, 64));
        if (n == 0) {
          int d = dt * 256 + w * 32 + r * 16 + q * 4 + e;
          size_t o = (size_t)(g0 + ii) * 2048 + d;
          out[o] = v + mm[o];
        }
      }
    }
  }
}

// ---------------------------------------------------------------------------
extern "C" void kernel_launch(void* const* d_in, const int* in_sizes, int n_in,
                              void* d_out, int out_size, void* d_ws, size_t ws_size,
                              hipStream_t stream) {
  const float* mm     = (const float*)d_in[0];
  const float* coords = (const float*)d_in[1];
  const float* Wcl    = (const float*)d_in[2];
  const float* Wcr    = (const float*)d_in[3];
  const float* Wcout  = (const float*)d_in[4];
  const float* Wfl    = (const float*)d_in[5];
  const float* Wfr    = (const float*)d_in[6];
  const float* Wfout  = (const float*)d_in[7];
  float* out = (float*)d_out;

  // workspace ~59 MB
  float* Mc = (float*)d_ws;                        // [16][2048] f32
  unsigned short* Fl  = (unsigned short*)(Mc + 16 * 2048);  // [1152][512] bf16
  unsigned short* Fr  = Fl + (size_t)1152 * 512;            // [1152][512] bf16
  unsigned short* WS  = Fr + (size_t)1152 * 512;            // 139264 gran x 8
  unsigned short* WS2 = WS + (size_t)139264 * 8;            // 262144 gran x 8
  unsigned short* mmb = WS2 + (size_t)262144 * 8;           // [1152][2048] bf16
  unsigned short* Pf  = mmb + (size_t)1152 * 2048;          // 44064 gran x 512 (45MB)

  k_mc<<<8, 256, 0, stream>>>(Wcl, Wcr, Wcout, Mc);
  k_prep<<<2304 + 1568, 256, 0, stream>>>(mm, Wfout, Mc, Wfl, Wfr, mmb, WS, WS2);
  k_proj_feat<<<dim3(16, 72), 256, 0, stream>>>(mmb, WS2, Fl, Fr);
  k_prod<<<11016, 256, 0, stream>>>(Fl, Fr, coords, Pf);
  k_pairwise<<<2304, 512, 0, stream>>>(Pf, WS, mm, out);
}

// Round 5
// 328.539 us; speedup vs baseline: 1.7014x; 1.1696x over previous
//
#include <hip/hip_runtime.h>

// B=32, N=36, D=2048, C=4, H=512.
// Out[b,i,d] = max_j [ sum_k Wfout[k,d]*(fl[i,k]*fr[j,k])
//                    + sum_ab Mc[ab,d]*(coords[i,a]*coords[j,b]) ] + mm[b,i,d]
// v3: coord branch collapsed via Mc[ab,d] = sum_h Wcl[a,h]Wcr[b,h]Wcout[h,d];
//     K: 1024 -> 544 = 17 kc-chunks.
// v4: k_pairwise register fix — even 16-iter conditional-free main loop +
//     peeled final chunk + __launch_bounds__(512,4) to pin VGPR+AGPR <= 128
//     (acc 72 AGPR + <=56 VGPR = v1's proven budget -> 2 blocks/CU).
// v4.1: identical resubmit (round 4 bench was an infra failure).

typedef __attribute__((ext_vector_type(8))) short short8;
typedef __attribute__((ext_vector_type(4))) short short4v;
typedef __attribute__((ext_vector_type(4))) float f32x4;

__device__ __forceinline__ float bf2f(unsigned short h) {
  return __uint_as_float(((unsigned int)h) << 16);
}
__device__ __forceinline__ unsigned short f2bf(float f) {
  unsigned int u = __float_as_uint(f);
  u += 0x7FFFu + ((u >> 16) & 1u);
  return (unsigned short)(u >> 16);
}
// async global->LDS, 16B per lane; lds dest is wave-uniform base + lane*16
__device__ __forceinline__ void gl2lds16(const void* g, void* l) {
  __builtin_amdgcn_global_load_lds(
      (const __attribute__((address_space(1))) unsigned int*)g,
      (__attribute__((address_space(3))) unsigned int*)l, 16, 0, 0);
}

// ---------------------------------------------------------------------------
// K_mc: Mc[ab][d] = sum_h Wcl[a,h] * Wcr[b,h] * Wcout[h,d]   (f32, 16x2048)
__global__ __launch_bounds__(256) void k_mc(
    const float* __restrict__ Wcl, const float* __restrict__ Wcr,
    const float* __restrict__ Wcout, float* __restrict__ Mc) {
  const int d = blockIdx.x * 256 + threadIdx.x;
  float acc[16];
#pragma unroll
  for (int i = 0; i < 16; ++i) acc[i] = 0.f;
  for (int h = 0; h < 512; ++h) {
    float wo = Wcout[(size_t)h * 2048 + d];
    float cl[4], cr[4];
#pragma unroll
    for (int a = 0; a < 4; ++a) {
      cl[a] = Wcl[a * 512 + h];
      cr[a] = Wcr[a * 512 + h];
    }
#pragma unroll
    for (int a = 0; a < 4; ++a) {
      float t = cl[a] * wo;
#pragma unroll
      for (int b = 0; b < 4; ++b) acc[a * 4 + b] += t * cr[b];
    }
  }
#pragma unroll
  for (int ab = 0; ab < 16; ++ab) Mc[(size_t)ab * 2048 + d] = acc[ab];
}

// ---------------------------------------------------------------------------
// K_prep: bid<2304: mm -> bf16 (mmb).
//         bid>=2304: weights -> MFMA fragment order:
//           WS  (A for k_pairwise): kc<16 from Wfout[k,d] (k=kc*32+q*8+e),
//                                   kc==16 from Mc[kk,d] (kk=q*8+e<16, else 0)
//           WS2 (B for k_proj_feat): (Wfl|Wfr)^T fragments.
__global__ __launch_bounds__(256) void k_prep(
    const float* __restrict__ mm, const float* __restrict__ Wfout,
    const float* __restrict__ Mc, const float* __restrict__ Wfl,
    const float* __restrict__ Wfr, unsigned short* __restrict__ mmb,
    unsigned short* __restrict__ WS, unsigned short* __restrict__ WS2) {
  const int bid = blockIdx.x;
  if (bid < 2304) {
    int idx = bid * 256 + threadIdx.x;  // 0 .. 1152*512-1
    int row = idx >> 9, h = idx & 511;
    float4 m4 = *(const float4*)(mm + (size_t)row * 2048 + h * 4);
    short4v o;
    o[0] = (short)f2bf(m4.x); o[1] = (short)f2bf(m4.y);
    o[2] = (short)f2bf(m4.z); o[3] = (short)f2bf(m4.w);
    *(short4v*)(mmb + (size_t)row * 2048 + h * 4) = o;
  } else {
    int gi = (bid - 2304) * 256 + threadIdx.x;  // 0..401407
    if (gi < 139264) {
      // WS granule gi = ((g2*17+kc)*4+q)*16+n ; elem e: d=g2*16+n, k=kc*32+q*8+e
      int n = gi & 15, qv = (gi >> 4) & 3, rest = gi >> 6;
      int kc = rest % 17, g2 = rest / 17;
      int d = g2 * 16 + n;
      short8 o;
      if (kc < 16) {
        int kbase = kc * 32 + qv * 8;
        const float* src = Wfout + (size_t)kbase * 2048 + d;
#pragma unroll
        for (int e = 0; e < 8; ++e) o[e] = (short)f2bf(src[(size_t)e * 2048]);
      } else if (qv < 2) {
        const float* src = Mc + (size_t)(qv * 8) * 2048 + d;
#pragma unroll
        for (int e = 0; e < 8; ++e) o[e] = (short)f2bf(src[(size_t)e * 2048]);
      } else {
#pragma unroll
        for (int e = 0; e < 8; ++e) o[e] = 0;
      }
      *(short8*)(WS + (size_t)gi * 8) = o;
    } else {
      // WS2 granule gj = ((cg*64+kc)*4+q)*16+n ; elem e: col=cg*16+n, dd=kc*32+q*8+e
      int gj = gi - 139264;
      int n = gj & 15, qv = (gj >> 4) & 3, kc = (gj >> 6) & 63, cg = gj >> 12;
      int col = cg * 16 + n;
      int dbase = kc * 32 + qv * 8;
      const float* src = (col < 512) ? (Wfl + (size_t)dbase * 512 + col)
                                     : (Wfr + (size_t)dbase * 512 + (col - 512));
      short8 o;
#pragma unroll
      for (int e = 0; e < 8; ++e) o[e] = (short)f2bf(src[(size_t)e * 512]);
      *(short8*)(WS2 + (size_t)gj * 8) = o;
    }
  }
}

// ---------------------------------------------------------------------------
// K3: feature projection O[row,col] = sum_dd mmb[row,dd]*Wlr[dd,col]
//  col<512 -> Fl[row][col] ; else -> Fr[row][col-512]   (bf16 out)
__global__ __launch_bounds__(256) void k_proj_feat(
    const unsigned short* __restrict__ mmb, const unsigned short* __restrict__ WS2,
    unsigned short* __restrict__ Fl, unsigned short* __restrict__ Fr) {
  const int tid = threadIdx.x;
  const int lane = tid & 63, w = tid >> 6;
  const int n = lane & 15, q = lane >> 4;
  const int m0 = blockIdx.y * 16;
  const int cg = blockIdx.x * 4 + w;  // 0..63
  const int c0 = cg * 16;

  f32x4 acc = {0.f, 0.f, 0.f, 0.f};
#pragma unroll 4
  for (int kc = 0; kc < 64; ++kc) {
    short8 a = *(const short8*)(mmb + (size_t)(m0 + n) * 2048 + kc * 32 + q * 8);
    short8 b = *(const short8*)(WS2 + (size_t)(cg * 64 + kc) * 512 + lane * 8);
    acc = __builtin_amdgcn_mfma_f32_16x16x32_bf16(a, b, acc, 0, 0, 0);
  }
#pragma unroll
  for (int e = 0; e < 4; ++e) {
    int row = m0 + q * 4 + e;
    int col = c0 + n;
    unsigned short v = f2bf(acc[e]);
    if (col < 512) Fl[(size_t)row * 512 + col] = v;
    else           Fr[(size_t)row * 512 + (col - 512)] = v;
  }
}

// ---------------------------------------------------------------------------
// K_prod: materialize pair "products" in MFMA B-fragment order, quad-packed.
// Granule id = (qg*17 + kc)*9 + t ; lane (q,n), elem e: k = kc*32 + q*8 + e.
//   t<8 : group g = qg*4 + (t>>1), col j = (t&1)*16 + n      (full tiles)
//   t=8 : group g = qg*4 + (n>>2), col j = 32 + (n&3)        (shared remainder)
// kc<16 : P = Fl[g,k] * Fr[b*36+j,k]                (feature products)
// kc==16: P = coords[g,a]*coords[b*36+j,bb], ab=q*8+e (<16), else 0
__global__ __launch_bounds__(256) void k_prod(
    const unsigned short* __restrict__ Fl, const unsigned short* __restrict__ Fr,
    const float* __restrict__ coords, unsigned short* __restrict__ Pf) {
  int idx = blockIdx.x * 256 + threadIdx.x;  // 0 .. 2,820,095
  int lane = idx & 63;
  int gran = idx >> 6;          // 0 .. 44063
  int qg = gran / 153;          // 153 = 17 kc * 9 t granules per quad-group
  int rem = gran - qg * 153;
  int kc = rem / 9;
  int t = rem - kc * 9;
  int n = lane & 15, q = lane >> 4;
  int b = qg / 9;
  int g, j;
  if (t < 8) { g = qg * 4 + (t >> 1); j = (t & 1) * 16 + n; }
  else       { g = qg * 4 + (n >> 2); j = 32 + (n & 3); }
  int rowj = b * 36 + j;
  short8 p;
  if (kc < 16) {
    int k0 = kc * 32 + q * 8;
    short8 cl8 = *(const short8*)(Fl + (size_t)g * 512 + k0);
    short8 cr8 = *(const short8*)(Fr + (size_t)rowj * 512 + k0);
#pragma unroll
    for (int e = 0; e < 8; ++e)
      p[e] = (short)f2bf(bf2f((unsigned short)cl8[e]) * bf2f((unsigned short)cr8[e]));
  } else if (q < 2) {
    float4 ci = *(const float4*)(coords + (size_t)g * 4);
    float4 cj = *(const float4*)(coords + (size_t)rowj * 4);
#pragma unroll
    for (int e = 0; e < 8; ++e) {
      int a = q * 2 + (e >> 2);  // 0..3 (q<2)
      float ca = (a == 0) ? ci.x : (a == 1) ? ci.y : (a == 2) ? ci.z : ci.w;
      float cb = ((e & 3) == 0) ? cj.x : ((e & 3) == 1) ? cj.y
               : ((e & 3) == 2) ? cj.z : cj.w;
      p[e] = (short)f2bf(ca * cb);
    }
  } else {
#pragma unroll
    for (int e = 0; e < 8; ++e) p[e] = 0;
  }
  *(short8*)(Pf + (size_t)idx * 8) = p;
}

// ---------------------------------------------------------------------------
// K4: streaming GEMM + max-over-j + residual. v1 structure, NK=17 chunks.
// Block: 512 thr (8 waves), one quad-group x 256-d tile. grid 2304 = qg*8+dt.
// Per chunk (32 k): stage 9 B-granules (9KB) via global_load_lds into dbuf
// LDS, 2 A-granules/wave from WS (reg dbuf), 18 MFMA/wave. acc 72 AGPR.
// Main loop: 16 even iterations, prefetch always valid (no guard); final
// chunk 16 peeled. launch_bounds(512,4) pins VGPR+AGPR <= 128 -> 2 blk/CU.
__global__ __launch_bounds__(512, 4) void k_pairwise(
    const unsigned short* __restrict__ Pf, const unsigned short* __restrict__ WS,
    const float* __restrict__ mm, float* __restrict__ out) {
  __shared__ __align__(16) unsigned short lB[2][9 * 512];  // 2 x 9 KB

  const int tid = threadIdx.x;
  const int lane = tid & 63, w = tid >> 6;  // w 0..7
  const int n = lane & 15, q = lane >> 4;
  const int bx = blockIdx.x;
  const int dt = bx & 7, qg = bx >> 3;  // dt 0..7, qg 0..287
  const int g0 = qg * 4;

  f32x4 acc[9][2];
#pragma unroll
  for (int t = 0; t < 9; ++t)
#pragma unroll
    for (int r = 0; r < 2; ++r) acc[t][r] = (f32x4){0.f, 0.f, 0.f, 0.f};

  // A granule (r, kc): WS + ((dt*16 + w*2 + r)*17 + kc)*512 + lane*8
  const unsigned short* Abase = WS + ((size_t)(dt * 16 + w * 2) * 17) * 512 + lane * 8;
  // B granule (kc, t): Pf + ((qg*17 + kc)*9 + t)*512 + lane*8
  const unsigned short* Bbase = Pf + (size_t)qg * 17 * 9 * 512;

  short8 aR[2], aN[2];
  // prologue: stage kc=0, load A(kc=0)
  gl2lds16(Bbase + (size_t)w * 512 + lane * 8, &lB[0][w * 512]);
  if (w == 0) gl2lds16(Bbase + (size_t)8 * 512 + lane * 8, &lB[0][8 * 512]);
  aR[0] = *(const short8*)(Abase);
  aR[1] = *(const short8*)(Abase + 17 * 512);
  __syncthreads();  // vmcnt(0) drain before barrier -> lB[0] ready

#pragma unroll 2
  for (int kc = 0; kc < 16; ++kc) {
    const int buf = kc & 1;
    // prefetch chunk kc+1 (always valid: kc+1 <= 16)
    const unsigned short* bn = Bbase + (size_t)((kc + 1) * 9) * 512 + lane * 8;
    gl2lds16(bn + (size_t)w * 512, &lB[buf ^ 1][w * 512]);
    if (w == 0) gl2lds16(bn + (size_t)8 * 512, &lB[buf ^ 1][8 * 512]);
    aN[0] = *(const short8*)(Abase + (size_t)(kc + 1) * 512);
    aN[1] = *(const short8*)(Abase + (size_t)(17 + kc + 1) * 512);

    short8 bb[9];
#pragma unroll
    for (int t = 0; t < 9; ++t)
      bb[t] = *(const short8*)(&lB[buf][t * 512 + lane * 8]);
#pragma unroll
    for (int t = 0; t < 9; ++t) {
      acc[t][0] = __builtin_amdgcn_mfma_f32_16x16x32_bf16(aR[0], bb[t], acc[t][0], 0, 0, 0);
      acc[t][1] = __builtin_amdgcn_mfma_f32_16x16x32_bf16(aR[1], bb[t], acc[t][1], 0, 0, 0);
    }
    __syncthreads();  // all waves done reading buf; staged buf^1 complete
    aR[0] = aN[0];
    aR[1] = aN[1];
  }

  // peeled final chunk kc=16 (in lB[0]), no prefetch
  {
    short8 bb[9];
#pragma unroll
    for (int t = 0; t < 9; ++t)
      bb[t] = *(const short8*)(&lB[0][t * 512 + lane * 8]);
#pragma unroll
    for (int t = 0; t < 9; ++t) {
      acc[t][0] = __builtin_amdgcn_mfma_f32_16x16x32_bf16(aR[0], bb[t], acc[t][0], 0, 0, 0);
      acc[t][1] = __builtin_amdgcn_mfma_f32_16x16x32_bf16(aR[1], bb[t], acc[t][1], 0, 0, 0);
    }
  }

  // epilogue: per (ii,r,e): max over full tiles 2ii,2ii+1 (j=n, 16+n) and the
  // shared tile's lanes with n>>2==ii (j=32+(n&3)); xor-reduce over 16 n-lanes.
#pragma unroll
  for (int r = 0; r < 2; ++r) {
#pragma unroll
    for (int e = 0; e < 4; ++e) {
      float vs = acc[8][r][e];
#pragma unroll
      for (int ii = 0; ii < 4; ++ii) {
        float v = fmaxf(acc[ii * 2][r][e], acc[ii * 2 + 1][r][e]);
        v = fmaxf(v, ((n >> 2) == ii) ? vs : -1e30f);
#pragma unroll
        for (int s = 1; s < 16; s <<= 1) v = fmaxf(v, __shfl_xor(v, s, 64));
        if (n == 0) {
          int d = dt * 256 + w * 32 + r * 16 + q * 4 + e;
          size_t o = (size_t)(g0 + ii) * 2048 + d;
          out[o] = v + mm[o];
        }
      }
    }
  }
}

// ---------------------------------------------------------------------------
extern "C" void kernel_launch(void* const* d_in, const int* in_sizes, int n_in,
                              void* d_out, int out_size, void* d_ws, size_t ws_size,
                              hipStream_t stream) {
  const float* mm     = (const float*)d_in[0];
  const float* coords = (const float*)d_in[1];
  const float* Wcl    = (const float*)d_in[2];
  const float* Wcr    = (const float*)d_in[3];
  const float* Wcout  = (const float*)d_in[4];
  const float* Wfl    = (const float*)d_in[5];
  const float* Wfr    = (const float*)d_in[6];
  const float* Wfout  = (const float*)d_in[7];
  float* out = (float*)d_out;

  // workspace ~59 MB
  float* Mc = (float*)d_ws;                        // [16][2048] f32
  unsigned short* Fl  = (unsigned short*)(Mc + 16 * 2048);  // [1152][512] bf16
  unsigned short* Fr  = Fl + (size_t)1152 * 512;            // [1152][512] bf16
  unsigned short* WS  = Fr + (size_t)1152 * 512;            // 139264 gran x 8
  unsigned short* WS2 = WS + (size_t)139264 * 8;            // 262144 gran x 8
  unsigned short* mmb = WS2 + (size_t)262144 * 8;           // [1152][2048] bf16
  unsigned short* Pf  = mmb + (size_t)1152 * 2048;          // 44064 gran x 512 (45MB)

  k_mc<<<8, 256, 0, stream>>>(Wcl, Wcr, Wcout, Mc);
  k_prep<<<2304 + 1568, 256, 0, stream>>>(mm, Wfout, Mc, Wfl, Wfr, mmb, WS, WS2);
  k_proj_feat<<<dim3(16, 72), 256, 0, stream>>>(mmb, WS2, Fl, Fr);
  k_prod<<<11016, 256, 0, stream>>>(Fl, Fr, coords, Pf);
  k_pairwise<<<2304, 512, 0, stream>>>(Pf, WS, mm, out);
}

// Round 6
// 293.412 us; speedup vs baseline: 1.9051x; 1.1197x over previous
//
#include <hip/hip_runtime.h>

// B=32, N=36, D=2048, C=4, H=512.
// Out[b,i,d] = max_j [ sum_k Wfout[k,d]*(fl[i,k]*fr[j,k])
//                    + sum_ab Mc[ab,d]*(coords[i,a]*coords[j,b]) ] + mm[b,i,d]
// v3: coord branch collapsed via Mc[ab,d]; K: 1024 -> 544 = 17 kc-chunks.
// v4: even 16-iter main loop + peeled final chunk + launch_bounds(512,4)
//     -> 60 VGPR + 72 AGPR <= 128/wave, 2 blocks/CU.  (k_pairwise 126us)
// v5: (a) XCD-clustered grid map: x=bx&7 (XCD), dt=(bx>>3)&7, qg=x*36+(bx>>6)
//         -> all 8 dt-siblings of a qg on ONE XCD, consecutive slots; Pf slice
//         read once from HBM then 7x L2-hit (was 8 XCDs x private L2).
//     (b) k_mc folded into k_prep (kc==16 WS granules compute Mc inline).

typedef __attribute__((ext_vector_type(8))) short short8;
typedef __attribute__((ext_vector_type(4))) short short4v;
typedef __attribute__((ext_vector_type(4))) float f32x4;

__device__ __forceinline__ float bf2f(unsigned short h) {
  return __uint_as_float(((unsigned int)h) << 16);
}
__device__ __forceinline__ unsigned short f2bf(float f) {
  unsigned int u = __float_as_uint(f);
  u += 0x7FFFu + ((u >> 16) & 1u);
  return (unsigned short)(u >> 16);
}
// async global->LDS, 16B per lane; lds dest is wave-uniform base + lane*16
__device__ __forceinline__ void gl2lds16(const void* g, void* l) {
  __builtin_amdgcn_global_load_lds(
      (const __attribute__((address_space(1))) unsigned int*)g,
      (__attribute__((address_space(3))) unsigned int*)l, 16, 0, 0);
}

// ---------------------------------------------------------------------------
// K_prep: bid<2304: mm -> bf16 (mmb).
//         bid>=2304: weights -> MFMA fragment order:
//           WS  (A for k_pairwise): kc<16 from Wfout[k,d] (k=kc*32+q*8+e),
//                kc==16: Mc[kk,d] = sum_h Wcl[a,h]Wcr[b,h]Wcout[h,d] computed
//                inline (kk=qv*8+e<16, a=kk>>2, b=kk&3; qv>=2 -> 0 pad)
//           WS2 (B for k_proj_feat): (Wfl|Wfr)^T fragments.
__global__ __launch_bounds__(256) void k_prep(
    const float* __restrict__ mm, const float* __restrict__ Wfout,
    const float* __restrict__ Wcl, const float* __restrict__ Wcr,
    const float* __restrict__ Wcout, const float* __restrict__ Wfl,
    const float* __restrict__ Wfr, unsigned short* __restrict__ mmb,
    unsigned short* __restrict__ WS, unsigned short* __restrict__ WS2) {
  const int bid = blockIdx.x;
  if (bid < 2304) {
    int idx = bid * 256 + threadIdx.x;  // 0 .. 1152*512-1
    int row = idx >> 9, h = idx & 511;
    float4 m4 = *(const float4*)(mm + (size_t)row * 2048 + h * 4);
    short4v o;
    o[0] = (short)f2bf(m4.x); o[1] = (short)f2bf(m4.y);
    o[2] = (short)f2bf(m4.z); o[3] = (short)f2bf(m4.w);
    *(short4v*)(mmb + (size_t)row * 2048 + h * 4) = o;
  } else {
    int gi = (bid - 2304) * 256 + threadIdx.x;  // 0..401407
    if (gi < 139264) {
      // WS granule gi = ((g2*17+kc)*4+q)*16+n ; elem e: d=g2*16+n, k=kc*32+q*8+e
      int n = gi & 15, qv = (gi >> 4) & 3, rest = gi >> 6;
      int kc = rest % 17, g2 = rest / 17;
      int d = g2 * 16 + n;
      short8 o;
      if (kc < 16) {
        int kbase = kc * 32 + qv * 8;
        const float* src = Wfout + (size_t)kbase * 2048 + d;
#pragma unroll
        for (int e = 0; e < 8; ++e) o[e] = (short)f2bf(src[(size_t)e * 2048]);
      } else if (qv < 2) {
        // inline Mc: o[e] = sum_h Wcl[qv*2+(e>>2),h]*Wcr[e&3,h]*Wcout[h,d]
        float acc[8];
#pragma unroll
        for (int e = 0; e < 8; ++e) acc[e] = 0.f;
        for (int h = 0; h < 512; ++h) {
          float wo = Wcout[(size_t)h * 2048 + d];
          float c0 = Wcl[(qv * 2 + 0) * 512 + h] * wo;
          float c1 = Wcl[(qv * 2 + 1) * 512 + h] * wo;
          float r0 = Wcr[h], r1 = Wcr[512 + h];
          float r2 = Wcr[1024 + h], r3 = Wcr[1536 + h];
          acc[0] += c0 * r0; acc[1] += c0 * r1;
          acc[2] += c0 * r2; acc[3] += c0 * r3;
          acc[4] += c1 * r0; acc[5] += c1 * r1;
          acc[6] += c1 * r2; acc[7] += c1 * r3;
        }
#pragma unroll
        for (int e = 0; e < 8; ++e) o[e] = (short)f2bf(acc[e]);
      } else {
#pragma unroll
        for (int e = 0; e < 8; ++e) o[e] = 0;
      }
      *(short8*)(WS + (size_t)gi * 8) = o;
    } else {
      // WS2 granule gj = ((cg*64+kc)*4+q)*16+n ; elem e: col=cg*16+n, dd=kc*32+q*8+e
      int gj = gi - 139264;
      int n = gj & 15, qv = (gj >> 4) & 3, kc = (gj >> 6) & 63, cg = gj >> 12;
      int col = cg * 16 + n;
      int dbase = kc * 32 + qv * 8;
      const float* src = (col < 512) ? (Wfl + (size_t)dbase * 512 + col)
                                     : (Wfr + (size_t)dbase * 512 + (col - 512));
      short8 o;
#pragma unroll
      for (int e = 0; e < 8; ++e) o[e] = (short)f2bf(src[(size_t)e * 512]);
      *(short8*)(WS2 + (size_t)gj * 8) = o;
    }
  }
}

// ---------------------------------------------------------------------------
// K3: feature projection O[row,col] = sum_dd mmb[row,dd]*Wlr[dd,col]
//  col<512 -> Fl[row][col] ; else -> Fr[row][col-512]   (bf16 out)
__global__ __launch_bounds__(256) void k_proj_feat(
    const unsigned short* __restrict__ mmb, const unsigned short* __restrict__ WS2,
    unsigned short* __restrict__ Fl, unsigned short* __restrict__ Fr) {
  const int tid = threadIdx.x;
  const int lane = tid & 63, w = tid >> 6;
  const int n = lane & 15, q = lane >> 4;
  const int m0 = blockIdx.y * 16;
  const int cg = blockIdx.x * 4 + w;  // 0..63
  const int c0 = cg * 16;

  f32x4 acc = {0.f, 0.f, 0.f, 0.f};
#pragma unroll 4
  for (int kc = 0; kc < 64; ++kc) {
    short8 a = *(const short8*)(mmb + (size_t)(m0 + n) * 2048 + kc * 32 + q * 8);
    short8 b = *(const short8*)(WS2 + (size_t)(cg * 64 + kc) * 512 + lane * 8);
    acc = __builtin_amdgcn_mfma_f32_16x16x32_bf16(a, b, acc, 0, 0, 0);
  }
#pragma unroll
  for (int e = 0; e < 4; ++e) {
    int row = m0 + q * 4 + e;
    int col = c0 + n;
    unsigned short v = f2bf(acc[e]);
    if (col < 512) Fl[(size_t)row * 512 + col] = v;
    else           Fr[(size_t)row * 512 + (col - 512)] = v;
  }
}

// ---------------------------------------------------------------------------
// K_prod: materialize pair "products" in MFMA B-fragment order, quad-packed.
// Granule id = (qg*17 + kc)*9 + t ; lane (q,n), elem e: k = kc*32 + q*8 + e.
//   t<8 : group g = qg*4 + (t>>1), col j = (t&1)*16 + n      (full tiles)
//   t=8 : group g = qg*4 + (n>>2), col j = 32 + (n&3)        (shared remainder)
// kc<16 : P = Fl[g,k] * Fr[b*36+j,k]                (feature products)
// kc==16: P = coords[g,a]*coords[b*36+j,bb], ab=q*8+e (<16), else 0
__global__ __launch_bounds__(256) void k_prod(
    const unsigned short* __restrict__ Fl, const unsigned short* __restrict__ Fr,
    const float* __restrict__ coords, unsigned short* __restrict__ Pf) {
  int idx = blockIdx.x * 256 + threadIdx.x;  // 0 .. 2,820,095
  int lane = idx & 63;
  int gran = idx >> 6;          // 0 .. 44063
  int qg = gran / 153;          // 153 = 17 kc * 9 t granules per quad-group
  int rem = gran - qg * 153;
  int kc = rem / 9;
  int t = rem - kc * 9;
  int n = lane & 15, q = lane >> 4;
  int b = qg / 9;
  int g, j;
  if (t < 8) { g = qg * 4 + (t >> 1); j = (t & 1) * 16 + n; }
  else       { g = qg * 4 + (n >> 2); j = 32 + (n & 3); }
  int rowj = b * 36 + j;
  short8 p;
  if (kc < 16) {
    int k0 = kc * 32 + q * 8;
    short8 cl8 = *(const short8*)(Fl + (size_t)g * 512 + k0);
    short8 cr8 = *(const short8*)(Fr + (size_t)rowj * 512 + k0);
#pragma unroll
    for (int e = 0; e < 8; ++e)
      p[e] = (short)f2bf(bf2f((unsigned short)cl8[e]) * bf2f((unsigned short)cr8[e]));
  } else if (q < 2) {
    float4 ci = *(const float4*)(coords + (size_t)g * 4);
    float4 cj = *(const float4*)(coords + (size_t)rowj * 4);
#pragma unroll
    for (int e = 0; e < 8; ++e) {
      int a = q * 2 + (e >> 2);  // 0..3 (q<2)
      float ca = (a == 0) ? ci.x : (a == 1) ? ci.y : (a == 2) ? ci.z : ci.w;
      float cb = ((e & 3) == 0) ? cj.x : ((e & 3) == 1) ? cj.y
               : ((e & 3) == 2) ? cj.z : cj.w;
      p[e] = (short)f2bf(ca * cb);
    }
  } else {
#pragma unroll
    for (int e = 0; e < 8; ++e) p[e] = 0;
  }
  *(short8*)(Pf + (size_t)idx * 8) = p;
}

// ---------------------------------------------------------------------------
// K4: streaming GEMM + max-over-j + residual. v4 structure, NK=17 chunks.
// Block: 512 thr (8 waves), one quad-group x 256-d tile.
// v5 grid map: x = bx&7 = XCD (round-robin dispatch), m = bx>>3;
//   dt = m&7, qg = x*36 + (m>>3)  -> 8 dt-siblings of each qg run on ONE XCD
//   at consecutive slots; Pf slice (153KB) is fetched once, then L2-hit.
// Per chunk (32 k): stage 9 B-granules (9KB) via global_load_lds into dbuf
// LDS, 2 A-granules/wave from WS (reg dbuf), 18 MFMA/wave. acc 72 AGPR.
// 16 even iterations (guard-free prefetch) + peeled chunk 16; 60 VGPR.
__global__ __launch_bounds__(512, 4) void k_pairwise(
    const unsigned short* __restrict__ Pf, const unsigned short* __restrict__ WS,
    const float* __restrict__ mm, float* __restrict__ out) {
  __shared__ __align__(16) unsigned short lB[2][9 * 512];  // 2 x 9 KB

  const int tid = threadIdx.x;
  const int lane = tid & 63, w = tid >> 6;  // w 0..7
  const int n = lane & 15, q = lane >> 4;
  const int bx = blockIdx.x;
  const int x = bx & 7;       // XCD id under round-robin dispatch
  const int m = bx >> 3;      // 0..287 per-XCD slot
  const int dt = m & 7;       // d-tile: siblings consecutive on the XCD
  const int qg = x * 36 + (m >> 3);  // qg clustered per XCD (bijective)
  const int g0 = qg * 4;

  f32x4 acc[9][2];
#pragma unroll
  for (int t = 0; t < 9; ++t)
#pragma unroll
    for (int r = 0; r < 2; ++r) acc[t][r] = (f32x4){0.f, 0.f, 0.f, 0.f};

  // A granule (r, kc): WS + ((dt*16 + w*2 + r)*17 + kc)*512 + lane*8
  const unsigned short* Abase = WS + ((size_t)(dt * 16 + w * 2) * 17) * 512 + lane * 8;
  // B granule (kc, t): Pf + ((qg*17 + kc)*9 + t)*512 + lane*8
  const unsigned short* Bbase = Pf + (size_t)qg * 17 * 9 * 512;

  short8 aR[2], aN[2];
  // prologue: stage kc=0, load A(kc=0)
  gl2lds16(Bbase + (size_t)w * 512 + lane * 8, &lB[0][w * 512]);
  if (w == 0) gl2lds16(Bbase + (size_t)8 * 512 + lane * 8, &lB[0][8 * 512]);
  aR[0] = *(const short8*)(Abase);
  aR[1] = *(const short8*)(Abase + 17 * 512);
  __syncthreads();  // vmcnt(0) drain before barrier -> lB[0] ready

#pragma unroll 2
  for (int kc = 0; kc < 16; ++kc) {
    const int buf = kc & 1;
    // prefetch chunk kc+1 (always valid: kc+1 <= 16)
    const unsigned short* bn = Bbase + (size_t)((kc + 1) * 9) * 512 + lane * 8;
    gl2lds16(bn + (size_t)w * 512, &lB[buf ^ 1][w * 512]);
    if (w == 0) gl2lds16(bn + (size_t)8 * 512, &lB[buf ^ 1][8 * 512]);
    aN[0] = *(const short8*)(Abase + (size_t)(kc + 1) * 512);
    aN[1] = *(const short8*)(Abase + (size_t)(17 + kc + 1) * 512);

    short8 bb[9];
#pragma unroll
    for (int t = 0; t < 9; ++t)
      bb[t] = *(const short8*)(&lB[buf][t * 512 + lane * 8]);
#pragma unroll
    for (int t = 0; t < 9; ++t) {
      acc[t][0] = __builtin_amdgcn_mfma_f32_16x16x32_bf16(aR[0], bb[t], acc[t][0], 0, 0, 0);
      acc[t][1] = __builtin_amdgcn_mfma_f32_16x16x32_bf16(aR[1], bb[t], acc[t][1], 0, 0, 0);
    }
    __syncthreads();  // all waves done reading buf; staged buf^1 complete
    aR[0] = aN[0];
    aR[1] = aN[1];
  }

  // peeled final chunk kc=16 (in lB[0]), no prefetch
  {
    short8 bb[9];
#pragma unroll
    for (int t = 0; t < 9; ++t)
      bb[t] = *(const short8*)(&lB[0][t * 512 + lane * 8]);
#pragma unroll
    for (int t = 0; t < 9; ++t) {
      acc[t][0] = __builtin_amdgcn_mfma_f32_16x16x32_bf16(aR[0], bb[t], acc[t][0], 0, 0, 0);
      acc[t][1] = __builtin_amdgcn_mfma_f32_16x16x32_bf16(aR[1], bb[t], acc[t][1], 0, 0, 0);
    }
  }

  // epilogue: per (ii,r,e): max over full tiles 2ii,2ii+1 (j=n, 16+n) and the
  // shared tile's lanes with n>>2==ii (j=32+(n&3)); xor-reduce over 16 n-lanes.
#pragma unroll
  for (int r = 0; r < 2; ++r) {
#pragma unroll
    for (int e = 0; e < 4; ++e) {
      float vs = acc[8][r][e];
#pragma unroll
      for (int ii = 0; ii < 4; ++ii) {
        float v = fmaxf(acc[ii * 2][r][e], acc[ii * 2 + 1][r][e]);
        v = fmaxf(v, ((n >> 2) == ii) ? vs : -1e30f);
#pragma unroll
        for (int s = 1; s < 16; s <<= 1) v = fmaxf(v, __shfl_xor(v, s, 64));
        if (n == 0) {
          int d = dt * 256 + w * 32 + r * 16 + q * 4 + e;
          size_t o = (size_t)(g0 + ii) * 2048 + d;
          out[o] = v + mm[o];
        }
      }
    }
  }
}

// ---------------------------------------------------------------------------
extern "C" void kernel_launch(void* const* d_in, const int* in_sizes, int n_in,
                              void* d_out, int out_size, void* d_ws, size_t ws_size,
                              hipStream_t stream) {
  const float* mm     = (const float*)d_in[0];
  const float* coords = (const float*)d_in[1];
  const float* Wcl    = (const float*)d_in[2];
  const float* Wcr    = (const float*)d_in[3];
  const float* Wcout  = (const float*)d_in[4];
  const float* Wfl    = (const float*)d_in[5];
  const float* Wfr    = (const float*)d_in[6];
  const float* Wfout  = (const float*)d_in[7];
  float* out = (float*)d_out;

  // workspace ~59 MB
  unsigned short* Fl  = (unsigned short*)d_ws;              // [1152][512] bf16
  unsigned short* Fr  = Fl + (size_t)1152 * 512;            // [1152][512] bf16
  unsigned short* WS  = Fr + (size_t)1152 * 512;            // 139264 gran x 8
  unsigned short* WS2 = WS + (size_t)139264 * 8;            // 262144 gran x 8
  unsigned short* mmb = WS2 + (size_t)262144 * 8;           // [1152][2048] bf16
  unsigned short* Pf  = mmb + (size_t)1152 * 2048;          // 44064 gran x 512 (45MB)

  k_prep<<<2304 + 1568, 256, 0, stream>>>(mm, Wfout, Wcl, Wcr, Wcout,
                                          Wfl, Wfr, mmb, WS, WS2);
  k_proj_feat<<<dim3(16, 72), 256, 0, stream>>>(mmb, WS2, Fl, Fr);
  k_prod<<<11016, 256, 0, stream>>>(Fl, Fr, coords, Pf);
  k_pairwise<<<2304, 512, 0, stream>>>(Pf, WS, mm, out);
}